// Round 5
// baseline (231.636 us; speedup 1.0000x reference)
//
#include <hip/hip_runtime.h>

// NMS3D: x (4,2,64,256,256) f32, 3x3x3 neighborhood-max excluding center,
// edge padding == index clamping (exact match, incl. zeroed boundary shell).
//
// R5: LDS slice staging. Block (64,8) = 8 waves; each wave owns one output
// row; block stages ROWS+2=10 rows x 1KB per slice into a double-buffered
// LDS slab (20 KB). Global loads fall 3.75 -> 1.56 per output row; the
// stencil reads rows from LDS (ds_read_b128), horizontal halo via shuffles
// as before. Staging load issued at body top, ds_write at body bottom ->
// one full compute body of load-latency cover. One barrier per slice.

constexpr int D_   = 64;
constexpr int H_   = 256;
constexpr int W_   = 256;
constexpr int HW_  = H_ * W_;
constexpr int NVOL = 8;     // B * CH
constexpr int DC   = 8;     // depth slices emitted per block
constexpr int ROWS = 8;     // output rows per block
constexpr int SROWS = ROWS + 2;

__device__ __forceinline__ float f3(float a, float b, float c) {
    return fmaxf(fmaxf(a, b), c);
}

__global__ __launch_bounds__(512, 4)
void nms3d(const float* __restrict__ x, float* __restrict__ out)
{
    __shared__ float buf[2][SROWS][W_];   // 2 x 10 KB

    const int tx = threadIdx.x;           // 0..63, W via float4
    const int ty = threadIdx.y;           // 0..7 -> wave id == row id
    const int h0 = blockIdx.y * ROWS;
    const int h  = h0 + ty;
    const int n  = blockIdx.z;
    const int z0 = blockIdx.x * DC;
    const int c  = tx << 2;

    const float* __restrict__ base  = x   + (size_t)n * D_ * HW_;
    float* __restrict__       obase = out + (size_t)n * D_ * HW_;

    // staging: wave ty fills LDS row ty+1 (global row h); edge waves double:
    // ty==0 also LDS row 0 (global h0-1 clamped), ty==ROWS-1 also LDS row
    // SROWS-1 (global h0+ROWS clamped).
    const int extra = (ty == 0) ? 0 : (ty == ROWS - 1 ? SROWS - 1 : -1);
    const int gx = (extra == 0) ? max(h0 - 1, 0) : min(h0 + ROWS, H_ - 1);

    // prestage slice z0-1 (clamped) into buf[0]
    {
        const float* sp = base + (size_t)max(z0 - 1, 0) * HW_;
        const float4 r = *(const float4*)(sp + h * W_ + c);
        *(float4*)&buf[0][ty + 1][c] = r;
        if (extra >= 0) {
            const float4 rx = *(const float4*)(sp + gx * W_ + c);
            *(float4*)&buf[0][extra][c] = rx;
        }
    }
    __syncthreads();

    // rolling depth state
    float4 vm9_pp = {0,0,0,0};  // vmax9[z-2]
    float4 vm9_p  = {0,0,0,0};  // vmax9[z-1]
    float4 cr8_p  = {0,0,0,0};  // cross8[z-1]
    float4 vprev  = {0,0,0,0};  // v[z-1]

#pragma unroll
    for (int t = 0; t < DC + 2; ++t) {
        const int zi  = z0 - 1 + t;
        const int cur = t & 1, nxt = cur ^ 1;

        // issue staging loads for slice zi+1 (consumed only at body bottom)
        float4 r, rx;
        const bool do_stage = (t < DC + 1);
        if (do_stage) {
            const float* sp = base + (size_t)min(zi + 1, D_ - 1) * HW_;
            r = *(const float4*)(sp + h * W_ + c);
            if (extra >= 0) rx = *(const float4*)(sp + gx * W_ + c);
        }

        // stencil on slice zi out of LDS
        const float4 a = *(const float4*)&buf[cur][ty    ][c];
        const float4 b = *(const float4*)&buf[cur][ty + 1][c];
        const float4 d = *(const float4*)&buf[cur][ty + 2][c];

        float4 va;
        va.x = fmaxf(a.x, d.x); va.y = fmaxf(a.y, d.y);
        va.z = fmaxf(a.z, d.z); va.w = fmaxf(a.w, d.w);

        float vaL = __shfl_up(va.w, 1);   if (tx == 0)  vaL = va.x;
        float vaR = __shfl_down(va.x, 1); if (tx == 63) vaR = va.w;
        float bL  = __shfl_up(b.w, 1);    if (tx == 0)  bL  = b.x;
        float bR  = __shfl_down(b.x, 1);  if (tx == 63) bR  = b.w;

        float4 hv;
        hv.x = f3(vaL, va.x, va.y);  hv.y = f3(va.x, va.y, va.z);
        hv.z = f3(va.y, va.z, va.w); hv.w = f3(va.z, va.w, vaR);
        float4 nb;
        nb.x = fmaxf(bL, b.y);   nb.y = fmaxf(b.x, b.z);
        nb.z = fmaxf(b.y, b.w);  nb.w = fmaxf(b.z, bR);

        float4 c8, cu;                       // cross8[zi], vmax9[zi]
        c8.x = fmaxf(hv.x, nb.x); c8.y = fmaxf(hv.y, nb.y);
        c8.z = fmaxf(hv.z, nb.z); c8.w = fmaxf(hv.w, nb.w);
        cu.x = fmaxf(c8.x, b.x);  cu.y = fmaxf(c8.y, b.y);
        cu.z = fmaxf(c8.z, b.z);  cu.w = fmaxf(c8.w, b.w);

        if (zi > z0) {
            // out[zi-1]: max_nc = max(vmax9[zi-2], cross8[zi-1], vmax9[zi])
            float4 mx, o;
            mx.x = f3(vm9_pp.x, cr8_p.x, cu.x);
            mx.y = f3(vm9_pp.y, cr8_p.y, cu.y);
            mx.z = f3(vm9_pp.z, cr8_p.z, cu.z);
            mx.w = f3(vm9_pp.w, cr8_p.w, cu.w);
            o.x = vprev.x > mx.x ? vprev.x : 0.0f;
            o.y = vprev.y > mx.y ? vprev.y : 0.0f;
            o.z = vprev.z > mx.z ? vprev.z : 0.0f;
            o.w = vprev.w > mx.w ? vprev.w : 0.0f;
            *(float4*)(obase + (size_t)(zi - 1) * HW_ + (size_t)h * W_ + c) = o;
        }
        vm9_pp = vm9_p; vm9_p = cu; cr8_p = c8; vprev = b;

        // land staged rows for slice zi+1, then barrier
        if (do_stage) {
            *(float4*)&buf[nxt][ty + 1][c] = r;
            if (extra >= 0) *(float4*)&buf[nxt][extra][c] = rx;
        }
        __syncthreads();
    }
}

extern "C" void kernel_launch(void* const* d_in, const int* in_sizes, int n_in,
                              void* d_out, int out_size, void* d_ws, size_t ws_size,
                              hipStream_t stream)
{
    const float* x = (const float*)d_in[0];
    float* out = (float*)d_out;
    dim3 block(64, ROWS, 1);                  // 512 threads = 8 waves
    dim3 grid(D_ / DC, H_ / ROWS, NVOL);      // 8 x 32 x 8 = 2048 blocks
    nms3d<<<grid, block, 0, stream>>>(x, out);
}